// Round 2
// baseline (3180.652 us; speedup 1.0000x reference)
//
#include <hip/hip_runtime.h>

// B=2048, T=128, D=5, H=256. Two sequential LSTM scans; batch-sliced
// persistent workgroups (16 rows/WG, grid=128, 8 waves of 64).
// Round 2: chunk-grouped weight loads with explicit 2-deep register
// double-buffering, x pre-staged in LDS, 1 barrier/step in both phases.

typedef __bf16 bf16x8 __attribute__((ext_vector_type(8)));
typedef float f32x4 __attribute__((ext_vector_type(4)));

#define MFMA16(A, B, C) __builtin_amdgcn_mfma_f32_16x16x32_bf16((A), (B), (C), 0, 0, 0)
#define HROW 264  // LDS row stride (elements); 528B row -> balanced banks for b128 reads

__device__ __forceinline__ float fast_sigmoid(float x) {
  float e = __builtin_amdgcn_exp2f(-1.4426950408889634f * x);
  return __builtin_amdgcn_rcpf(1.0f + e);
}
__device__ __forceinline__ float fast_tanh(float x) {
  float e = __builtin_amdgcn_exp2f(2.8853900817779268f * x);
  return 1.0f - 2.0f * __builtin_amdgcn_rcpf(e + 1.0f);
}
__device__ __forceinline__ float lrelu(float x) { return x >= 0.0f ? x : 0.01f * x; }

// ---------------- prep: pack weights into per-(gate-tile,chunk,lane) fragments ----------------
// wpack fragment (gt,c,lane): 8 bf16 = W[g=gt*16+(lane&15)][k = c*32+(lane>>4)*8 + 0..7]
__global__ void pack_gates_k(const float* __restrict__ Whh, const float* __restrict__ Wih,
                             const float* __restrict__ bih, const float* __restrict__ bhh,
                             __bf16* __restrict__ wpack, __bf16* __restrict__ ihpack,
                             float* __restrict__ bias) {
  int lane = threadIdx.x;
  int blk = blockIdx.x;
  if (blk < 512) {  // W_hh chunks 0..7 (k<256)
    int gt = blk >> 3, c = blk & 7;
    int g = gt * 16 + (lane & 15);
    int k0 = c * 32 + (lane >> 4) * 8;
    bf16x8 v;
#pragma unroll
    for (int j = 0; j < 8; ++j) v[j] = (__bf16)Whh[g * 256 + k0 + j];
    *(bf16x8*)(wpack + ((size_t)(gt * 8 + c) * 64 + lane) * 8) = v;
  } else if (blk < 576) {  // W_ih chunk (k=256..287 -> x[0..4], zero pad)
    int gt = blk - 512;
    int g = gt * 16 + (lane & 15);
    int kk = (lane >> 4) * 8;
    bf16x8 v;
#pragma unroll
    for (int j = 0; j < 8; ++j) {
      float f = (kk + j < 5) ? Wih[g * 5 + kk + j] : 0.0f;
      v[j] = (__bf16)f;
    }
    *(bf16x8*)(ihpack + ((size_t)gt * 64 + lane) * 8) = v;
  } else {  // combined bias
    int g = (blk - 576) * 64 + lane;
    bias[g] = bih[g] + bhh[g];
  }
}

__global__ void pack_enc_k(const float* __restrict__ Wenc, __bf16* __restrict__ encpack) {
  int lane = threadIdx.x;
  int gt = blockIdx.x >> 3, c = blockIdx.x & 7;
  int j_row = gt * 16 + (lane & 15);
  int k0 = c * 32 + (lane >> 4) * 8;
  bf16x8 v;
#pragma unroll
  for (int j = 0; j < 8; ++j) v[j] = (__bf16)Wenc[j_row * 512 + k0 + j];  // cols 0..255 of (256,512)
  *(bf16x8*)(encpack + ((size_t)(gt * 8 + c) * 64 + lane) * 8) = v;
}

__global__ void pack_out_k(const float* __restrict__ Wout, __bf16* __restrict__ outpack) {
  int lane = threadIdx.x;
  int c = blockIdx.x;
  int d = lane & 15;
  int k0 = c * 32 + (lane >> 4) * 8;
  bf16x8 v;
#pragma unroll
  for (int j = 0; j < 8; ++j) v[j] = (d < 5) ? (__bf16)Wout[d * 256 + k0 + j] : (__bf16)0.0f;
  *(bf16x8*)(outpack + ((size_t)c * 64 + lane) * 8) = v;
}

// ---------------- main fused kernel ----------------

// 8 weight chunk-groups (one per k-chunk), each 8 fragments (one per owned
// gate-tile m = q*2+p), ping-pong double-buffered 2 deep.
#define GATES(ACCS)                                                                   \
  {                                                                                   \
    bf16x8 bbA[8], bbB[8];                                                            \
    _Pragma("unroll") for (int m = 0; m < 8; ++m) bbA[m] = wbase[m][0];               \
    _Pragma("unroll") for (int m = 0; m < 8; ++m) bbB[m] = wbase[m][64];              \
    _Pragma("unroll") for (int cc = 0; cc < 4; ++cc) {                                \
      _Pragma("unroll") for (int m = 0; m < 8; ++m)                                   \
          ACCS[m] = MFMA16(a[cc * 2], bbA[m], ACCS[m]);                               \
      if (cc < 3) {                                                                   \
        _Pragma("unroll") for (int m = 0; m < 8; ++m) bbA[m] = wbase[m][(cc * 2 + 2) * 64]; \
      }                                                                               \
      _Pragma("unroll") for (int m = 0; m < 8; ++m)                                   \
          ACCS[m] = MFMA16(a[cc * 2 + 1], bbB[m], ACCS[m]);                           \
      if (cc < 3) {                                                                   \
        _Pragma("unroll") for (int m = 0; m < 8; ++m) bbB[m] = wbase[m][(cc * 2 + 3) * 64]; \
      }                                                                               \
    }                                                                                 \
    _Pragma("unroll") for (int m = 0; m < 8; ++m) ACCS[m] = MFMA16(ax, wih[m], ACCS[m]); \
  }

#define ACTIV_STORE_H(ACCS, WI)                                        \
  _Pragma("unroll") for (int p = 0; p < 2; ++p) {                      \
    _Pragma("unroll") for (int r = 0; r < 4; ++r) {                    \
      float ig = fast_sigmoid(ACCS[p][r]);                             \
      float fg = fast_sigmoid(ACCS[2 + p][r]);                         \
      float gg = fast_tanh(ACCS[4 + p][r]);                            \
      float og = fast_sigmoid(ACCS[6 + p][r]);                         \
      float cn = fg * c_reg[p][r] + ig * gg;                           \
      c_reg[p][r] = cn;                                                \
      hbuf[WI][lgrp * 4 + r][(ut2 + p) * 16 + col] = (__bf16)(og * fast_tanh(cn)); \
    }                                                                  \
  }

__global__ __launch_bounds__(512, 2) void rnn_fused(
    const float* __restrict__ sk, const float* __restrict__ initx,
    const bf16x8* __restrict__ Wg, const bf16x8* __restrict__ Wgih, const float* __restrict__ biasg,
    const bf16x8* __restrict__ Wf, const bf16x8* __restrict__ Wfih, const float* __restrict__ biasf,
    const bf16x8* __restrict__ Wenc, const float* __restrict__ benc,
    const bf16x8* __restrict__ Wout, const float* __restrict__ bout,
    float* __restrict__ out) {
  __shared__ __attribute__((aligned(16))) __bf16 xbuf[128][16][8];  // 32 KB: all encoder x
  __shared__ __attribute__((aligned(16))) __bf16 hbuf[2][16][HROW]; // 16.5 KB: h ping-pong
  __shared__ __attribute__((aligned(16))) __bf16 xt[8][16][8];      // 2 KB: per-wave x transpose
  __shared__ __attribute__((aligned(16))) __bf16 zslot[8];          // 16B zeros

  const int tid = threadIdx.x;
  const int lane = tid & 63;
  const int wv = tid >> 6;     // wave 0..7; owns hidden units [wv*32, wv*32+32)
  const int col = lane & 15;   // MFMA: A-row / C-col
  const int lgrp = lane >> 4;  // MFMA: k-group / C-row-group
  const int b0 = blockIdx.x * 16;
  const int ut2 = wv * 2;

  // ---- init LDS ----
  for (int i = tid; i < 2 * 16 * HROW; i += 512) (&hbuf[0][0][0])[i] = (__bf16)0.0f;
  for (int i = tid; i < 8 * 16 * 8; i += 512) (&xt[0][0][0])[i] = (__bf16)0.0f;
  if (tid < 8) zslot[tid] = (__bf16)0.0f;
  // pre-stage ALL encoder x: xbuf[t][r][0..7] = {x[b0+r][t][0..4], 0,0,0}
  for (int idx = tid; idx < 2048; idx += 512) {
    int r = idx >> 7, t = idx & 127;
    const float* p = sk + ((size_t)(b0 + r) * 128 + t) * 5;
    bf16x8 v;
    v[0] = (__bf16)p[0]; v[1] = (__bf16)p[1]; v[2] = (__bf16)p[2];
    v[3] = (__bf16)p[3]; v[4] = (__bf16)p[4];
    v[5] = (__bf16)0.0f; v[6] = (__bf16)0.0f; v[7] = (__bf16)0.0f;
    *(bf16x8*)&xbuf[t][r][0] = v;
  }

  float c_reg[2][4];
#pragma unroll
  for (int p = 0; p < 2; ++p)
#pragma unroll
    for (int r = 0; r < 4; ++r) c_reg[p][r] = 0.0f;

  // ---- encoder phase-resident weights ----
  const bf16x8* wbase[8];
  bf16x8 wih[8];
  float bias_v[8];
#pragma unroll
  for (int m = 0; m < 8; ++m) {
    const int q = m >> 1, p = m & 1, gt = q * 16 + ut2 + p;
    wbase[m] = Wf + gt * 512 + lane;  // fragment (gt, c, lane) at wbase[m] + c*64
    wih[m] = Wfih[gt * 64 + lane];
    bias_v[m] = biasf[q * 256 + (ut2 + p) * 16 + col];
  }
  __syncthreads();

  bf16x8 a[8], ax;
#pragma unroll
  for (int c = 0; c < 8; ++c) a[c] = *(const bf16x8*)&hbuf[0][col][c * 32 + lgrp * 8];
  ax = *(const bf16x8*)((lgrp == 0) ? &xbuf[0][col][0] : &zslot[0]);

  // -------- encoder: 128 steps, 1 barrier/step --------
  for (int t = 0; t < 128; ++t) {
    const int wi = (t + 1) & 1;
    f32x4 accs[8];
#pragma unroll
    for (int m = 0; m < 8; ++m) {
      const float bv = bias_v[m];
      accs[m] = (f32x4){bv, bv, bv, bv};
    }
    GATES(accs);
    ACTIV_STORE_H(accs, wi);
    __syncthreads();
#pragma unroll
    for (int c = 0; c < 8; ++c) a[c] = *(const bf16x8*)&hbuf[wi][col][c * 32 + lgrp * 8];
    const int tn = (t < 127) ? t + 1 : 127;
    ax = *(const bf16x8*)((lgrp == 0) ? &xbuf[tn][col][0] : &zslot[0]);
  }

  // -------- transition: hidden/cell = lrelu(W_enc[:, :256] @ {h_f, c_f} + b) --------
  // a[] holds h_f (hbuf[0]); stage c_f into hbuf[1]
#pragma unroll
  for (int p = 0; p < 2; ++p)
#pragma unroll
    for (int r = 0; r < 4; ++r)
      hbuf[1][lgrp * 4 + r][(ut2 + p) * 16 + col] = (__bf16)c_reg[p][r];
  __syncthreads();
  {
    bf16x8 ac[8];
#pragma unroll
    for (int c = 0; c < 8; ++c) ac[c] = *(const bf16x8*)&hbuf[1][col][c * 32 + lgrp * 8];
#pragma unroll
    for (int p = 0; p < 2; ++p) {
      const int et = ut2 + p;
      const bf16x8* ebase = Wenc + et * 512 + lane;
      bf16x8 eb[8];
#pragma unroll
      for (int c = 0; c < 8; ++c) eb[c] = ebase[c * 64];
      const float bv = benc[et * 16 + col];
      f32x4 hacc = {bv, bv, bv, bv};
      f32x4 cacc = {bv, bv, bv, bv};
#pragma unroll
      for (int c = 0; c < 8; ++c) {
        hacc = MFMA16(a[c], eb[c], hacc);
        cacc = MFMA16(ac[c], eb[c], cacc);
      }
#pragma unroll
      for (int r = 0; r < 4; ++r) {
        hbuf[0][lgrp * 4 + r][et * 16 + col] = (__bf16)lrelu(hacc[r]);  // h(0) of gen
        c_reg[p][r] = lrelu(cacc[r]);                                   // c(0) of gen
      }
    }
  }
  if (tid < 80) {  // x(0) of generator = init_inputs (reuse xbuf[0]; d=5..7 already 0)
    int r = tid / 5, d = tid - (tid / 5) * 5;
    xbuf[0][r][d] = (__bf16)initx[(b0 + r) * 5 + d];
  }

  // ---- generator phase-resident weights ----
  bf16x8 wout_f[8];
#pragma unroll
  for (int m = 0; m < 8; ++m) {
    const int q = m >> 1, p = m & 1, gt = q * 16 + ut2 + p;
    wbase[m] = Wg + gt * 512 + lane;
    wih[m] = Wgih[gt * 64 + lane];
    bias_v[m] = biasg[q * 256 + (ut2 + p) * 16 + col];
  }
#pragma unroll
  for (int c = 0; c < 8; ++c) wout_f[c] = Wout[c * 64 + lane];
  const float bo_v = (col < 5) ? bout[col] : 0.0f;

  __syncthreads();
#pragma unroll
  for (int c = 0; c < 8; ++c) a[c] = *(const bf16x8*)&hbuf[0][col][c * 32 + lgrp * 8];
  ax = *(const bf16x8*)((lgrp == 0) ? &xbuf[0][col][0] : &zslot[0]);

  // -------- generator: 128 steps, 1 barrier/step --------
  for (int t = 0; t < 128; ++t) {
    const int wi = 1 - (t & 1);
    f32x4 accs[8];
#pragma unroll
    for (int m = 0; m < 8; ++m) {
      const float bv = bias_v[m];
      accs[m] = (f32x4){bv, bv, bv, bv};
    }
    GATES(accs);
    ACTIV_STORE_H(accs, wi);
    __syncthreads();
#pragma unroll
    for (int c = 0; c < 8; ++c) a[c] = *(const bf16x8*)&hbuf[wi][col][c * 32 + lgrp * 8];
    // out(t) = lrelu(W_out @ h(t) + b_out) — computed redundantly by ALL waves so
    // each wave builds its own x(t+1) fragment via a private LDS transpose (no barrier).
    f32x4 oacc = {bo_v, bo_v, bo_v, bo_v};
#pragma unroll
    for (int c = 0; c < 8; ++c) oacc = MFMA16(a[c], wout_f[c], oacc);
    if (col < 5) {
#pragma unroll
      for (int r = 0; r < 4; ++r) {
        float v = lrelu(oacc[r]);
        if (wv == 0) out[((size_t)(b0 + lgrp * 4 + r) * 128 + t) * 5 + col] = v;
        xt[wv][lgrp * 4 + r][col] = (__bf16)v;  // d=5..7 stay zero
      }
    }
    ax = *(const bf16x8*)((lgrp == 0) ? &xt[wv][col][0] : &zslot[0]);
  }
}

extern "C" void kernel_launch(void* const* d_in, const int* in_sizes, int n_in,
                              void* d_out, int out_size, void* d_ws, size_t ws_size,
                              hipStream_t stream) {
  const float* sk = (const float*)d_in[0];
  const float* initx = (const float*)d_in[1];
  const float* W_ih = (const float*)d_in[2];
  const float* W_hh = (const float*)d_in[3];
  const float* b_ih = (const float*)d_in[4];
  const float* b_hh = (const float*)d_in[5];
  const float* W_ih_f = (const float*)d_in[6];
  const float* W_hh_f = (const float*)d_in[7];
  const float* b_ih_f = (const float*)d_in[8];
  const float* b_hh_f = (const float*)d_in[9];
  const float* W_enc = (const float*)d_in[14];
  const float* b_enc = (const float*)d_in[15];
  const float* W_out = (const float*)d_in[16];
  const float* b_out = (const float*)d_in[17];

  char* ws = (char*)d_ws;
  __bf16* Wg = (__bf16*)(ws + 0);           // 524288 B
  __bf16* Wf = (__bf16*)(ws + 524288);      // 524288 B
  __bf16* Wgih = (__bf16*)(ws + 1048576);   // 65536 B
  __bf16* Wfih = (__bf16*)(ws + 1114112);   // 65536 B
  __bf16* Wenc = (__bf16*)(ws + 1179648);   // 131072 B
  __bf16* Wout = (__bf16*)(ws + 1310720);   // 8192 B
  float* biasg = (float*)(ws + 1318912);    // 4096 B
  float* biasf = (float*)(ws + 1323008);    // 4096 B

  pack_gates_k<<<592, 64, 0, stream>>>(W_hh, W_ih, b_ih, b_hh, Wg, Wgih, biasg);
  pack_gates_k<<<592, 64, 0, stream>>>(W_hh_f, W_ih_f, b_ih_f, b_hh_f, Wf, Wfih, biasf);
  pack_enc_k<<<128, 64, 0, stream>>>(W_enc, Wenc);
  pack_out_k<<<8, 64, 0, stream>>>(W_out, Wout);

  rnn_fused<<<128, 512, 0, stream>>>(
      sk, initx,
      (const bf16x8*)Wg, (const bf16x8*)Wgih, biasg,
      (const bf16x8*)Wf, (const bf16x8*)Wfih, biasf,
      (const bf16x8*)Wenc, b_enc,
      (const bf16x8*)Wout, b_out,
      (float*)d_out);
}